// Round 9
// baseline (9520.161 us; speedup 1.0000x reference)
//
#include <hip/hip_runtime.h>
#include <hip/hip_bf16.h>

#define Bz 32
#define Tz 1024
#define Iz 64
#define Hz 512
#define Az 16
#define NF 4     // worker blocks (2 pairs x 2 col-halves)

// d_out layout (FP32 elems): out [B,T,A] | hn [1,B,H] | rnn_out [B,T,H]
#define OFF_HN  (Bz*Tz*Az)
#define OFF_RNN (OFF_HN + Bz*Hz)

typedef unsigned short u16;
typedef unsigned int u32;
typedef unsigned long long u64;
typedef __attribute__((ext_vector_type(8))) unsigned short u16x8;
typedef __attribute__((ext_vector_type(8))) __bf16 bf16x8;
typedef __attribute__((ext_vector_type(4))) float f32x4;

// ws layout (bytes)
#define WS_FLAGS 0x00000u   // int[1025*NF] = 16,400 B (zeroed each launch)
#define WS_RING  0x21000u   // u16[4][32][512] = 131072 B
#define WS_WHT   0x41000u   // u16[512*512] bf16 whhT [n][k] = 512 KB
#define WS_WIH   0xC1000u   // u16[64*512] bf16 = 64 KB
#define WS_W1T   0xD1000u   // u16[512*512] bf16 w1t [n][k]; end 0x151000
#define WS_ZERO  0x05000u   // memset span: covers flags only

__device__ __forceinline__ u16 f2bf(float f) {
  union { float f; unsigned int i; } x; x.f = f;
  unsigned int r = (x.i + 0x7FFFu + ((x.i >> 16) & 1u)) >> 16;
  return (u16)r;
}
__device__ __forceinline__ float bf2f(u16 u) {
  union { unsigned int i; float f; } x; x.i = ((unsigned int)u) << 16; return x.f;
}
__device__ __forceinline__ float sigmoidf_(float z) {
  return 1.0f / (1.0f + __expf(-z));
}

// ---------------------------------------------------------------------------
// Prep: fp32 -> bf16. whhT and w1t TRANSPOSED to [n][k]; wih layout-preserved.
// ---------------------------------------------------------------------------
__global__ void prep_kernel(const float* __restrict__ whh,
                            const float* __restrict__ wih,
                            const float* __restrict__ w1,
                            u16* __restrict__ whhT,
                            u16* __restrict__ wih_bf,
                            u16* __restrict__ w1t_bf) {
  int idx = blockIdx.x * 256 + threadIdx.x;
  if (idx < 262144) {
    int n = idx >> 9, k = idx & 511;
    whhT[idx] = f2bf(whh[k * Hz + n]);        // whhT[n][k] <- whh[k][n]
  } else if (idx < 294912) {
    int i = idx - 262144;
    wih_bf[i] = f2bf(wih[i]);
  } else if (idx < 557056) {
    int j = idx - 294912;
    int n = j >> 9, k = j & 511;
    w1t_bf[n * Hz + k] = f2bf(w1[k * Hz + n]);  // [n][k] <- [k][n]
  }
}

// ---------------------------------------------------------------------------
// xproj: out_rnn[b*T+t][n] = sum_i inp[b][t][i] * wih[i][n]  (fp32 result).
// Scan reads this per step and overwrites it in place with h_t.
// ---------------------------------------------------------------------------
__global__ __launch_bounds__(256, 2) void xproj_kernel(
    const float* __restrict__ inp,   // [32768 rows][64]
    const u16* __restrict__ wih_bf,  // [i=64][n=512]
    float* __restrict__ xp)          // [32768][512] (= out_rnn region)
{
  __shared__ u16 wl[512][72];  // col-major [n][i], pad 8

  const int tid  = threadIdx.x;
  const int lane = tid & 63;
  const int wv   = tid >> 6;
  const int ln   = lane & 15;
  const int q    = lane >> 4;

#pragma unroll
  for (int i = 0; i < Iz; ++i) {
    wl[tid][i]       = wih_bf[i * Hz + tid];
    wl[tid + 256][i] = wih_bf[i * Hz + tid + 256];
  }
  __syncthreads();

  const size_t row0 = (size_t)blockIdx.x * 64 + wv * 16;
  const float* ip = inp + (row0 + ln) * Iz + q * 8;
  f32x4 x0 = *(const f32x4*)(ip);
  f32x4 x1 = *(const f32x4*)(ip + 4);
  f32x4 x2 = *(const f32x4*)(ip + 32);
  f32x4 x3 = *(const f32x4*)(ip + 36);
  u16x8 ax0, ax1;
#pragma unroll
  for (int j = 0; j < 4; ++j) {
    ax0[j]     = f2bf(x0[j]);
    ax0[4 + j] = f2bf(x1[j]);
    ax1[j]     = f2bf(x2[j]);
    ax1[4 + j] = f2bf(x3[j]);
  }

  for (int nt = 0; nt < 32; ++nt) {
    bf16x8 b0 = __builtin_bit_cast(bf16x8, *(const u16x8*)&wl[nt * 16 + ln][q * 8]);
    bf16x8 b1 = __builtin_bit_cast(bf16x8, *(const u16x8*)&wl[nt * 16 + ln][32 + q * 8]);
    f32x4 a = {0.f, 0.f, 0.f, 0.f};
    a = __builtin_amdgcn_mfma_f32_16x16x32_bf16(
        __builtin_bit_cast(bf16x8, ax0), b0, a, 0, 0, 0);
    a = __builtin_amdgcn_mfma_f32_16x16x32_bf16(
        __builtin_bit_cast(bf16x8, ax1), b1, a, 0, 0, 0);
#pragma unroll
    for (int r = 0; r < 4; ++r)
      xp[(row0 + q * 4 + r) * Hz + nt * 16 + ln] = a[r];
  }
}

// ---------------------------------------------------------------------------
// Scan R15 = R10 pair design + 8x exchange dedup via LDS staging + xproj.
// R14 post-mortem killed the >RF-residency approach (3 attempts, 8-14k
// cyc/step). Re-derivation: the R10 PAIR design (W[:, 256 own cols] =
// 256 KB/block = 128 frag regs/wave) had NO residency problem; its cost was
// all 8 waves separately gathering the same 8 KB partner half = 64 KB/step
// of scattered coherent loads (64 KB / 4.3 B-per-cyc == R10's 15.4k
// cyc/step exactly). Fix: stage the partner half into LDS ONCE per step
// (512 thr x 16 B = 8 KB, one pipelined coherent round trip), then all
// waves read A-frags from LDS.
//   - 16 blocks launched; only bid&7 < 2 work: workers {0,8,1,9}. If
//     blockIdx round-robins XCDs (measured m09), pair members (0,8) and
//     (1,9) share an XCD L2 -> faster exchange. Heuristic only: protocol
//     is agent-scope, correct on any placement.
//   - pair p=bid&7 owns rows [16p,16p+16); qh=bid>>3 owns cols [256qh,+256).
//   - own-half h in hl[16][256] (XOR-swizzled 16B chunks: chunk^=(row&7));
//     partner half staged into pl[16][256] (same swizzle).
//   - own-half 16 MFMA pre-poll; partner 16 MFMA after staging barrier.
//   - xproj precomputed into out_rnn; read at step top, overwritten with h.
// Protocol per R10 (proven): ring atomic-stores -> __syncthreads (drain) ->
// relaxed flag store -> output stores. Consumer: relaxed poll (exit only
// after load RETURNS 1) -> coherent loads issued strictly later. Ring depth
// 4 + <=1-step pair lockstep => slot reuse race-free.
// MFMA 16x16x32 bf16 (HW-proven): A m=lane&15,k=q*8+j; B n=lane&15,k=q*8+j;
//                                 C/D col=lane&15, row=q*4+reg.
// ---------------------------------------------------------------------------
__global__ __launch_bounds__(512, 1) void rnn_scan_kernel(
    const float* __restrict__ hn,    // [B][H] fp32
    const u16* __restrict__ whhT,    // [n=H][k=H] bf16
    float* __restrict__ out_rnn,     // [B][T][H] fp32, pre-filled with xproj
    float* __restrict__ out_hn,      // [B][H] fp32
    int* __restrict__ flags,         // [1025][NF] (zeroed)
    u16* __restrict__ hbuf)          // [4][B][H] bf16 ring (linear layout)
{
  __shared__ u16 hl[16][256];   // own-half h, swizzled: 8 KB
  __shared__ u16 pl[16][256];   // partner-half h, swizzled: 8 KB

  const int tid  = threadIdx.x;
  const int lane = tid & 63;
  const int w    = tid >> 6;        // wave 0..7 -> own cols [32w,32w+32)
  const int ln   = lane & 15;
  const int q    = lane >> 4;
  const int bid  = blockIdx.x;
  if ((bid & 7) >= 2) return;       // 12 of 16 blocks idle (XCD spacing)
  const int p     = bid & 7;        // pair = row group
  const int qh    = bid >> 3;       // col half
  const int r0    = p * 16;
  const int cbase = qh * 256;
  const int obase = 256 - cbase;    // partner col base
  const int c0    = cbase + w * 32; // wave's global col base
  const int fid      = p * 2 + qh;
  const int fpartner = p * 2 + (1 - qh);

  // ---- W_hh B-frags for own cols, ALL k: bhh[2 ct][16 ks] = 128 regs/wave
  bf16x8 bhh[2][16];
#pragma unroll
  for (int ct = 0; ct < 2; ++ct)
#pragma unroll
    for (int ks = 0; ks < 16; ++ks)
      bhh[ct][ks] = __builtin_bit_cast(
          bf16x8, *(const u16x8*)(whhT + (size_t)(c0 + ct * 16 + ln) * Hz +
                                  ks * 32 + q * 8));

  // ---- h0 init: own rows x own cols -> hl (swizzled) + ring slot 0
  {
    const int row = tid >> 5;          // 0..15
    const int ch  = tid & 31;          // 16B chunk (8 cols)
    const float* hp = hn + (size_t)(r0 + row) * Hz + cbase + ch * 8;
    f32x4 a = *(const f32x4*)(hp);
    f32x4 b = *(const f32x4*)(hp + 4);
    u16x8 px;
#pragma unroll
    for (int j = 0; j < 4; ++j) { px[j] = f2bf(a[j]); px[4 + j] = f2bf(b[j]); }
    *(u16x8*)&hl[row][(ch ^ (row & 7)) * 8] = px;
    u64 two[2] = {0, 0};
    *(u16x8*)two = px;
    u64* rp = (u64*)(hbuf) + ((size_t)(r0 + row) * Hz + cbase + ch * 8) / 4;
    __hip_atomic_store(rp,     two[0], __ATOMIC_RELAXED, __HIP_MEMORY_SCOPE_AGENT);
    __hip_atomic_store(rp + 1, two[1], __ATOMIC_RELAXED, __HIP_MEMORY_SCOPE_AGENT);
  }
  __syncthreads();
  if (tid == 0)
    __hip_atomic_store(&flags[fid], 1, __ATOMIC_RELAXED,
                       __HIP_MEMORY_SCOPE_AGENT);

  for (int t = 0; t < Tz; ++t) {
    // Phase 1: xp loads (consumed at epilogue ~1500 cyc later)
    float xp[2][4];
#pragma unroll
    for (int r = 0; r < 4; ++r) {
      const float* xrow =
          out_rnn + ((size_t)(r0 + q * 4 + r) * Tz + t) * Hz + c0 + ln;
      xp[0][r] = xrow[0];
      xp[1][r] = xrow[16];
    }

    f32x4 acc[2];
    acc[0] = (f32x4){0.f, 0.f, 0.f, 0.f};
    acc[1] = (f32x4){0.f, 0.f, 0.f, 0.f};

    // Phase 2: own-half k (16 MFMA) — pre-poll, hides under exchange
#pragma unroll
    for (int ks = 0; ks < 8; ++ks) {
      bf16x8 A = __builtin_bit_cast(
          bf16x8, *(const u16x8*)&hl[ln][((ks * 4 + q) ^ (ln & 7)) * 8]);
      acc[0] = __builtin_amdgcn_mfma_f32_16x16x32_bf16(
          A, bhh[0][qh * 8 + ks], acc[0], 0, 0, 0);
      acc[1] = __builtin_amdgcn_mfma_f32_16x16x32_bf16(
          A, bhh[1][qh * 8 + ks], acc[1], 0, 0, 0);
    }

    // Phase 3: poll partner flag (wave-uniform; exit only after load==1)
    {
      int got;
      do {
        got = __hip_atomic_load(&flags[t * NF + fpartner], __ATOMIC_RELAXED,
                                __HIP_MEMORY_SCOPE_AGENT);
      } while (!got);
    }

    // Phase 4: stage partner 8 KB half -> pl (ONE coherent RT, coalesced)
    {
      const int row = tid >> 5;
      const int ch  = tid & 31;
      const u64* src = (const u64*)(hbuf + (size_t)(t & 3) * (Bz * Hz)) +
                       ((size_t)(r0 + row) * Hz + obase + ch * 8) / 4;
      u64 v0 = __hip_atomic_load(src,     __ATOMIC_RELAXED,
                                 __HIP_MEMORY_SCOPE_AGENT);
      u64 v1 = __hip_atomic_load(src + 1, __ATOMIC_RELAXED,
                                 __HIP_MEMORY_SCOPE_AGENT);
      u64* dst = (u64*)&pl[row][(ch ^ (row & 7)) * 8];
      dst[0] = v0;
      dst[1] = v1;
    }
    __syncthreads();  // pl ready; also fences all waves' phase-2 hl reads

    // Phase 5: partner-half k (16 MFMA) from pl
#pragma unroll
    for (int ks = 0; ks < 8; ++ks) {
      bf16x8 A = __builtin_bit_cast(
          bf16x8, *(const u16x8*)&pl[ln][((ks * 4 + q) ^ (ln & 7)) * 8]);
      acc[0] = __builtin_amdgcn_mfma_f32_16x16x32_bf16(
          A, bhh[0][(1 - qh) * 8 + ks], acc[0], 0, 0, 0);
      acc[1] = __builtin_amdgcn_mfma_f32_16x16x32_bf16(
          A, bhh[1][(1 - qh) * 8 + ks], acc[1], 0, 0, 0);
    }

    // Phase 6: h = sigmoid(acc + xp); ring store (linear) + hl store (swz)
    float hv[2][4];
    u16* ring_next = hbuf + (size_t)((t + 1) & 3) * (Bz * Hz);
#pragma unroll
    for (int ct = 0; ct < 2; ++ct)
#pragma unroll
      for (int r = 0; r < 4; ++r) {
        hv[ct][r] = sigmoidf_(acc[ct][r] + xp[ct][r]);
        u32 mine  = (u32)f2bf(hv[ct][r]);
        u32 other = (u32)__shfl_xor((int)mine, 1, 64);
        if (!(ln & 1)) {
          u32 pk = mine | (other << 16);
          const int row_l = q * 4 + r;
          const int col_l = w * 32 + ct * 16 + ln;  // own-half local col
          __hip_atomic_store(
              (u32*)(ring_next + (size_t)(r0 + row_l) * Hz + cbase + col_l),
              pk, __ATOMIC_RELAXED, __HIP_MEMORY_SCOPE_AGENT);
          *(u32*)&hl[row_l][((col_l >> 3) ^ (row_l & 7)) * 8 + (col_l & 7)] = pk;
        }
      }
    __syncthreads();  // drains ring stores; hl writes visible; pl reads done
    if (tid == 0)
      __hip_atomic_store(&flags[(t + 1) * NF + fid], 1, __ATOMIC_RELAXED,
                         __HIP_MEMORY_SCOPE_AGENT);

    // Phase 7: output stores AFTER the flag release — off the critical path
#pragma unroll
    for (int ct = 0; ct < 2; ++ct)
#pragma unroll
      for (int r = 0; r < 4; ++r) {
        const int grow = r0 + q * 4 + r;
        const int gcol = c0 + ct * 16 + ln;
        out_rnn[((size_t)grow * Tz + t) * Hz + gcol] = hv[ct][r];
        if (t == Tz - 1) out_hn[(size_t)grow * Hz + gcol] = hv[ct][r];
      }
  }
}

// ---------------------------------------------------------------------------
// FC head (unchanged, R3-lineage).
// ---------------------------------------------------------------------------
__global__ __launch_bounds__(256, 2) void fc_kernel(
    const float* __restrict__ X,  // [32768][512] fp32 (= rnn_out)
    const u16* __restrict__ w1t,  // [n=512][k=512] bf16
    const float* __restrict__ b1, // [512] fp32
    const float* __restrict__ w2, // [n=512][a=16] fp32
    const float* __restrict__ b2, // [16] fp32
    float* __restrict__ out)      // [32768][16] fp32
{
  __shared__ u16 smem[18432];     // 36 KB
  u16* As = smem;                 // [128][72]
  u16* Bs = smem + 9216;          // [128][72]
  u16* Ht = smem;                 // [128][136] (reused, 34816 B)

  const int tid  = threadIdx.x;
  const int lane = tid & 63;
  const int wv   = tid >> 6;
  const int ln   = lane & 15, q = lane >> 4;
  const int mq   = (wv & 1) * 64, nq = (wv >> 1) * 64;
  const size_t r0 = (size_t)blockIdx.x * 128;
  const int om = tid >> 1;          // output row 0..127
  const int oa = (tid & 1) * 8;     // output col half

  float oacc[8];
#pragma unroll
  for (int j = 0; j < 8; ++j) oacc[j] = 0.f;

  for (int nt = 0; nt < 4; ++nt) {
    const int n0 = nt * 128;
    f32x4 acc[4][4];
#pragma unroll
    for (int mi = 0; mi < 4; ++mi)
#pragma unroll
      for (int ni = 0; ni < 4; ++ni) acc[mi][ni] = (f32x4){0.f, 0.f, 0.f, 0.f};

    for (int kb = 0; kb < 8; ++kb) {
      const int K0 = kb * 64;
      __syncthreads();  // prior frag/Ht reads done before restaging
      for (int i = tid; i < 1024; i += 256) {
        int row = i >> 3, c = (i & 7) * 8;
        f32x4 lo = *(const f32x4*)(X + (r0 + row) * Hz + K0 + c);
        f32x4 hi = *(const f32x4*)(X + (r0 + row) * Hz + K0 + c + 4);
        u16x8 pxx;
#pragma unroll
        for (int j = 0; j < 4; ++j) { pxx[j] = f2bf(lo[j]); pxx[4 + j] = f2bf(hi[j]); }
        *(u16x8*)(As + row * 72 + c) = pxx;
      }
      for (int i = tid; i < 1024; i += 256) {
        int row = i >> 3, c = (i & 7) * 8;
        *(u16x8*)(Bs + row * 72 + c) =
            *(const u16x8*)(w1t + (size_t)(n0 + row) * Hz + K0 + c);
      }
      __syncthreads();
#pragma unroll
      for (int kt = 0; kt < 2; ++kt) {
        bf16x8 af[4], bfr[4];
#pragma unroll
        for (int mi = 0; mi < 4; ++mi)
          af[mi] = __builtin_bit_cast(
              bf16x8,
              *(const u16x8*)(As + (mq + mi * 16 + ln) * 72 + kt * 32 + q * 8));
#pragma unroll
        for (int ni = 0; ni < 4; ++ni)
          bfr[ni] = __builtin_bit_cast(
              bf16x8,
              *(const u16x8*)(Bs + (nq + ni * 16 + ln) * 72 + kt * 32 + q * 8));
#pragma unroll
        for (int mi = 0; mi < 4; ++mi)
#pragma unroll
          for (int ni = 0; ni < 4; ++ni)
            acc[mi][ni] = __builtin_amdgcn_mfma_f32_16x16x32_bf16(
                af[mi], bfr[ni], acc[mi][ni], 0, 0, 0);
      }
    }
    __syncthreads();  // MFMA frag reads done before Ht overwrite

    // hidden = relu(acc + b1) -> Ht bf16
#pragma unroll
    for (int ni = 0; ni < 4; ++ni) {
      float bb = b1[n0 + nq + ni * 16 + ln];
#pragma unroll
      for (int mi = 0; mi < 4; ++mi)
#pragma unroll
        for (int r = 0; r < 4; ++r) {
          float h = fmaxf(acc[mi][ni][r] + bb, 0.f);
          Ht[(mq + mi * 16 + q * 4 + r) * 136 + nq + ni * 16 + ln] = f2bf(h);
        }
    }
    __syncthreads();

    // fc2 partial over this n-slice into registers
    for (int n = 0; n < 128; ++n) {
      float hv = bf2f(Ht[om * 136 + n]);
      const float* w2p = w2 + (size_t)(n0 + n) * Az + oa;
#pragma unroll
      for (int j = 0; j < 8; ++j) oacc[j] += hv * w2p[j];
    }
  }

#pragma unroll
  for (int j = 0; j < 8; ++j)
    out[(r0 + om) * Az + oa + j] = sigmoidf_(oacc[j] + b2[oa + j]);
}

extern "C" void kernel_launch(void* const* d_in, const int* in_sizes, int n_in,
                              void* d_out, int out_size, void* d_ws, size_t ws_size,
                              hipStream_t stream) {
  // Permutation detection from in_sizes (insurance; proven harmless)
  int idx_inp = 0, idx_hn = 1, idx_wih = 3, idx_b1 = 5, idx_w2 = 6, idx_b2 = 7;
  int amb1 = -1, amb2 = -1, found = 0;
  for (int i = 0; i < 8 && i < n_in; ++i) {
    switch (in_sizes[i]) {
      case 2097152: idx_inp = i; found |= 1; break;
      case 16384:   idx_hn  = i; found |= 2; break;
      case 32768:   idx_wih = i; found |= 4; break;
      case 512:     idx_b1  = i; found |= 8; break;
      case 8192:    idx_w2  = i; found |= 16; break;
      case 16:      idx_b2  = i; found |= 32; break;
      case 262144:  if (amb1 < 0) amb1 = i; else amb2 = i; break;
    }
  }
  int idx_whh = 2, idx_w1 = 4;  // dict-order fallback
  if (amb1 >= 0 && amb2 >= 0 && found == 63) {
    if (idx_b1 < idx_inp) { idx_w1 = amb1; idx_whh = amb2; }
    else                  { idx_whh = amb1; idx_w1 = amb2; }
  }

  const float* inp = (const float*)d_in[idx_inp];
  const float* hn  = (const float*)d_in[idx_hn];
  const float* whh = (const float*)d_in[idx_whh];
  const float* wih = (const float*)d_in[idx_wih];
  const float* w1  = (const float*)d_in[idx_w1];
  const float* b1  = (const float*)d_in[idx_b1];
  const float* w2  = (const float*)d_in[idx_w2];
  const float* b2  = (const float*)d_in[idx_b2];

  float* out     = (float*)d_out;
  float* out_hn  = out + OFF_HN;
  float* out_rnn = out + OFF_RNN;

  char* ws    = (char*)d_ws;
  int* flags  = (int*)(ws + WS_FLAGS);
  u16* hbuf   = (u16*)(ws + WS_RING);
  u16* whhT   = (u16*)(ws + WS_WHT);
  u16* wih_bf = (u16*)(ws + WS_WIH);
  u16* w1t_bf = (u16*)(ws + WS_W1T);

  (void)hipMemsetAsync(d_ws, 0, WS_ZERO, stream);
  prep_kernel<<<dim3(2176), dim3(256), 0, stream>>>(whh, wih, w1,
                                                    whhT, wih_bf, w1t_bf);
  xproj_kernel<<<dim3(512), dim3(256), 0, stream>>>(inp, wih_bf, out_rnn);
  rnn_scan_kernel<<<dim3(16), dim3(512), 0, stream>>>(
      hn, whhT, out_rnn, out_hn, flags, hbuf);
  fc_kernel<<<dim3(256), dim3(256), 0, stream>>>(
      out_rnn, w1t_bf, b1, w2, b2, out);
}